// Round 12
// baseline (195.512 us; speedup 1.0000x reference)
//
#include <hip/hip_runtime.h>
#include <hip/hip_fp16.h>

// GCN encoder: out = A @ ( relu(A @ (X W1)) W2 ),  A = COO scatter (dst <- src)
// N=100000 nodes, E=1600000 edges, F_IN=128, H1=64, H2=32, all f32.
//
// Round 12: spmm1 waves made persistent (grid-stride over nodes): the 32-load
// W2 register preload happens once per wave instead of once per node (was >50%
// of spmm1's VMEM issue). Rest identical to round 11.

constexpr int N_NODES = 100000;
constexpr int N_EDGES = 1600000;
constexpr int F_IN = 128;
constexpr int H1 = 64;
constexpr int H2 = 32;
constexpr int BSHIFT = 9;                         // 512 nodes per bucket
constexpr int BNODES = 1 << BSHIFT;
constexpr int NBUCK = (N_NODES + BNODES - 1) / BNODES;  // 196
constexpr int CAP = 10240;                        // per-bucket capacity (mean 8163)
constexpr int CHUNK = 4096;                       // edges per binning workgroup
constexpr int P1_WGS = (N_EDGES + CHUNK - 1) / CHUNK;  // 391
constexpr int GEMM_WGS = (N_NODES + 255) / 256;        // 391
constexpr int SP1_BLOCKS = 2048;                  // persistent spmm1 grid
constexpr int SP1_WAVES = SP1_BLOCKS * 4;         // 8192 waves

// ---------------- cursor init: cursor[b] = b*CAP ---------------------------
__global__ __launch_bounds__(256) void init_cursors(int* __restrict__ cursor)
{
    int t = threadIdx.x;
    if (t < NBUCK) cursor[t] = t * CAP;
}

// ---- pass1: gemm1 blocks first, then binning blocks -----------------------
// staging record: .x = src | (dst_low9 << 17)   (src < 2^17), .y = w bits
__global__ __launch_bounds__(256) void pass1_bin_gemm1(
    const int* __restrict__ src, const int* __restrict__ dst,
    const float* __restrict__ w, int* __restrict__ cursor,
    int2* __restrict__ staging,
    const float* __restrict__ X, const float* __restrict__ W1,
    __half* __restrict__ xw1out)
{
    __shared__ float smem[F_IN * H1];                // 32 KiB (both roles)

    if (blockIdx.x < GEMM_WGS) {
        // ---------------- gemm_xw1 role ----------------
        for (int i = threadIdx.x; i < F_IN * H1; i += 256) smem[i] = W1[i];
        __syncthreads();
        int row = blockIdx.x * 256 + threadIdx.x;
        if (row >= N_NODES) return;
        const float4* xr = reinterpret_cast<const float4*>(X + (size_t)row * F_IN);
        float4 acc[H1 / 4];
#pragma unroll
        for (int j = 0; j < H1 / 4; ++j) acc[j] = make_float4(0.f, 0.f, 0.f, 0.f);
        for (int k4 = 0; k4 < F_IN / 4; ++k4) {
            float4 xv = xr[k4];
#pragma unroll
            for (int kk = 0; kk < 4; ++kk) {
                float xk = (kk == 0) ? xv.x : (kk == 1) ? xv.y
                         : (kk == 2) ? xv.z : xv.w;
                const float4* wr = reinterpret_cast<const float4*>(
                    &smem[(k4 * 4 + kk) * H1]);
#pragma unroll
                for (int j = 0; j < H1 / 4; ++j) {
                    float4 wv = wr[j];
                    acc[j].x += xk * wv.x;
                    acc[j].y += xk * wv.y;
                    acc[j].z += xk * wv.z;
                    acc[j].w += xk * wv.w;
                }
            }
        }
        __half2* oh = reinterpret_cast<__half2*>(xw1out + (size_t)row * H1);
#pragma unroll
        for (int j = 0; j < H1 / 4; ++j) {
            oh[j * 2 + 0] = __floats2half2_rn(acc[j].x, acc[j].y);
            oh[j * 2 + 1] = __floats2half2_rn(acc[j].z, acc[j].w);
        }
        return;
    }

    // ---------------- binning role (16 edges per thread) ----------------
    int* lcnt  = (int*)smem;        // [256] counters, then reused as cursors
    int* lbase = lcnt + 256;        // [256] reserved global bases

    int e0 = (blockIdx.x - GEMM_WGS) * CHUNK;
    int nhere = N_EDGES - e0; if (nhere > CHUNK) nhere = CHUNK;  // 4096 or 2560

    lcnt[threadIdx.x] = 0;
    __syncthreads();

    int   es[16];
    int   ed[16];
    float ew[16];
    {
        bool v = (threadIdx.x * 16) < nhere;         // nhere % 16 == 0
        int tb = e0 + threadIdx.x * 16;
        if (v) {
            const int4* sp = reinterpret_cast<const int4*>(src + tb);
            const int4* dp = reinterpret_cast<const int4*>(dst + tb);
            const float4* wp = reinterpret_cast<const float4*>(w + tb);
#pragma unroll
            for (int q = 0; q < 4; ++q) {
                int4 sv = sp[q], dv = dp[q]; float4 wv = wp[q];
                es[4*q+0]=sv.x; es[4*q+1]=sv.y; es[4*q+2]=sv.z; es[4*q+3]=sv.w;
                ed[4*q+0]=dv.x; ed[4*q+1]=dv.y; ed[4*q+2]=dv.z; ed[4*q+3]=dv.w;
                ew[4*q+0]=wv.x; ew[4*q+1]=wv.y; ew[4*q+2]=wv.z; ew[4*q+3]=wv.w;
            }
        } else {
#pragma unroll
            for (int k = 0; k < 16; ++k) { es[k]=0; ed[k]=-1; ew[k]=0.f; }
        }
    }
#pragma unroll
    for (int k = 0; k < 16; ++k)
        if (ed[k] >= 0) atomicAdd(&lcnt[ed[k] >> BSHIFT], 1);
    __syncthreads();
    if (threadIdx.x < NBUCK) {
        int c = lcnt[threadIdx.x];
        lbase[threadIdx.x] = (c > 0) ? atomicAdd(&cursor[threadIdx.x], c) : 0;
    }
    __syncthreads();
    lcnt[threadIdx.x] = 0;                            // reuse as cursors
    __syncthreads();
#pragma unroll
    for (int k = 0; k < 16; ++k) {
        if (ed[k] >= 0) {
            int b = ed[k] >> BSHIFT;
            int r = atomicAdd(&lcnt[b], 1);
            int pos = lbase[b] + r;
            if (pos < (b + 1) * CAP)                  // capacity guard
                staging[pos] = make_int2(
                    es[k] | ((ed[k] & (BNODES - 1)) << 17),
                    __float_as_int(ew[k]));
        }
    }
}

// ---- sort_bucket: LDS counting sort of one bucket -> csr + seg ------------
__global__ __launch_bounds__(1024) void sort_bucket(
    const int* __restrict__ cursor, const int2* __restrict__ staging,
    int2* __restrict__ csr, int2* __restrict__ seg)
{
    __shared__ int  lcnt[BNODES];                    // 2 KiB
    __shared__ int  lofs[BNODES];                    // 2 KiB
    __shared__ int2 sorted[CAP];                     // 80 KiB

    int b = blockIdx.x, t = threadIdx.x;
    int base = b * CAP;
    int cnt = cursor[b] - base; if (cnt > CAP) cnt = CAP;

    if (t < BNODES) lcnt[t] = 0;
    __syncthreads();

    for (int j = t; j < cnt; j += 1024)
        atomicAdd(&lcnt[(staging[base + j].x >> 17) & (BNODES - 1)], 1);
    __syncthreads();

    int v = (t < BNODES) ? lcnt[t] : 0;
    if (t < BNODES) lofs[t] = v;
    __syncthreads();
    for (int off = 1; off < BNODES; off <<= 1) {
        int add = (t >= off && t < BNODES) ? lofs[t - off] : 0;
        __syncthreads();
        if (t < BNODES) lofs[t] += add;
        __syncthreads();
    }
    if (t < BNODES) {
        int excl = lofs[t] - v;
        seg[b * BNODES + t] = make_int2(base + excl, v);
        lcnt[t] = excl;                              // running cursors
    }
    __syncthreads();

    for (int j = t; j < cnt; j += 1024) {
        int2 c = staging[base + j];
        int node = (c.x >> 17) & (BNODES - 1);
        int pos = atomicAdd(&lcnt[node], 1);
        sorted[pos] = make_int2(c.x & 0x1FFFF, c.y);
    }
    __syncthreads();

    for (int j = t; j < cnt; j += 1024) csr[base + j] = sorted[j];
}

// ---- layer1 SpMM + fused relu + W2: persistent waves, grid-stride ---------
// Lane = (parity, feature-pair). W2 column preloaded in 32 VGPRs ONCE per
// wave; wave then strides over ~12 nodes.
__global__ __launch_bounds__(256) void spmm1_fused(
    const int2* __restrict__ seg, const int2* __restrict__ csr,
    const __half* __restrict__ xin, const float* __restrict__ W2,
    __half* __restrict__ h1w2h)
{
    int tid = blockIdx.x * 256 + threadIdx.x;
    int wave = tid >> 6;
    int f = tid & 63;
    int par = f >> 5;                                // edge parity
    int f2 = f & 31;                                 // feature pair: 2f2, 2f2+1

    // preload W2[par*32 .. +31][f2] once per wave (loop-invariant)
    float w2r[32];
#pragma unroll
    for (int kk = 0; kk < 32; ++kk)
        w2r[kk] = W2[(par * 32 + kk) * H2 + f2];

    for (int node = wave; node < N_NODES; node += SP1_WAVES) {
        int2 s = seg[node];
        int end = s.x + s.y;
        float2 a0 = make_float2(0.f, 0.f), a1 = make_float2(0.f, 0.f);
        float2 a2 = make_float2(0.f, 0.f), a3 = make_float2(0.f, 0.f);
        int e = s.x + par;
        for (; e + 6 < end; e += 8) {                // this parity: e,e+2,e+4,e+6
            int2 c0 = csr[e], c1 = csr[e + 2], c2 = csr[e + 4], c3 = csr[e + 6];
            float2 x0 = __half22float2(
                *reinterpret_cast<const __half2*>(&xin[(size_t)c0.x * H1 + 2 * f2]));
            float2 x1 = __half22float2(
                *reinterpret_cast<const __half2*>(&xin[(size_t)c1.x * H1 + 2 * f2]));
            float2 x2 = __half22float2(
                *reinterpret_cast<const __half2*>(&xin[(size_t)c2.x * H1 + 2 * f2]));
            float2 x3 = __half22float2(
                *reinterpret_cast<const __half2*>(&xin[(size_t)c3.x * H1 + 2 * f2]));
            float w0 = __int_as_float(c0.y), w1 = __int_as_float(c1.y);
            float w2v = __int_as_float(c2.y), w3 = __int_as_float(c3.y);
            a0.x += w0 * x0.x; a0.y += w0 * x0.y;
            a1.x += w1 * x1.x; a1.y += w1 * x1.y;
            a2.x += w2v * x2.x; a2.y += w2v * x2.y;
            a3.x += w3 * x3.x; a3.y += w3 * x3.y;
        }
        for (; e < end; e += 2) {
            int2 c = csr[e];
            float2 x = __half22float2(
                *reinterpret_cast<const __half2*>(&xin[(size_t)c.x * H1 + 2 * f2]));
            float wv = __int_as_float(c.y);
            a0.x += wv * x.x; a0.y += wv * x.y;
        }
        float rx = (a0.x + a1.x) + (a2.x + a3.x);
        float ry = (a0.y + a1.y) + (a2.y + a3.y);
        rx += __shfl_xor(rx, 32, 64);                // combine parities
        ry += __shfl_xor(ry, 32, 64);
        rx = fmaxf(rx, 0.f); ry = fmaxf(ry, 0.f);    // relu(h1) pair

        // o[j=f2] partial over k = par*32 + kk; pair p = 16*par + kk/2
        float o = 0.f;
#pragma unroll
        for (int kk = 0; kk < 32; kk += 2) {
            int p = 16 * par + (kk >> 1);
            o += __shfl(rx, p, 64) * w2r[kk];
            o += __shfl(ry, p, 64) * w2r[kk + 1];
        }
        o += __shfl_xor(o, 32, 64);
        if (f < 32)
            h1w2h[(size_t)node * H2 + f2] = __float2half(o);
    }
}

// ---- layer 2 SpMM: wave per node, quarter-waves on edge slots, half2 ------
__global__ __launch_bounds__(256) void spmm_csr32h(
    const int2* __restrict__ seg, const int2* __restrict__ csr,
    const __half* __restrict__ xin, float* __restrict__ out)
{
    int gid = blockIdx.x * 256 + threadIdx.x;        // grid covers N*64 exactly
    int node = gid >> 6;
    int lane = gid & 63;
    int slot = lane >> 4;                            // edge slot 0..3
    int f2 = lane & 15;                              // feature pair: 2f2, 2f2+1

    int2 s = seg[node];
    int end = s.x + s.y;
    float2 a0 = make_float2(0.f, 0.f), a1 = make_float2(0.f, 0.f);
    float2 a2 = make_float2(0.f, 0.f), a3 = make_float2(0.f, 0.f);
    int e = s.x + slot;
    for (; e + 12 < end; e += 16) {                  // slot: e,e+4,e+8,e+12
        int2 c0 = csr[e], c1 = csr[e + 4], c2 = csr[e + 8], c3 = csr[e + 12];
        float2 x0 = __half22float2(
            *reinterpret_cast<const __half2*>(&xin[(size_t)c0.x * H2 + 2 * f2]));
        float2 x1 = __half22float2(
            *reinterpret_cast<const __half2*>(&xin[(size_t)c1.x * H2 + 2 * f2]));
        float2 x2 = __half22float2(
            *reinterpret_cast<const __half2*>(&xin[(size_t)c2.x * H2 + 2 * f2]));
        float2 x3 = __half22float2(
            *reinterpret_cast<const __half2*>(&xin[(size_t)c3.x * H2 + 2 * f2]));
        float w0 = __int_as_float(c0.y), w1 = __int_as_float(c1.y);
        float w2v = __int_as_float(c2.y), w3 = __int_as_float(c3.y);
        a0.x += w0 * x0.x; a0.y += w0 * x0.y;
        a1.x += w1 * x1.x; a1.y += w1 * x1.y;
        a2.x += w2v * x2.x; a2.y += w2v * x2.y;
        a3.x += w3 * x3.x; a3.y += w3 * x3.y;
    }
    for (; e < end; e += 4) {
        int2 c = csr[e];
        float2 x = __half22float2(
            *reinterpret_cast<const __half2*>(&xin[(size_t)c.x * H2 + 2 * f2]));
        float wv = __int_as_float(c.y);
        a0.x += wv * x.x; a0.y += wv * x.y;
    }
    float ox = (a0.x + a1.x) + (a2.x + a3.x);
    float oy = (a0.y + a1.y) + (a2.y + a3.y);
    ox += __shfl_xor(ox, 16, 64); oy += __shfl_xor(oy, 16, 64);
    ox += __shfl_xor(ox, 32, 64); oy += __shfl_xor(oy, 32, 64);
    if (lane < 16)
        *reinterpret_cast<float2*>(&out[(size_t)node * H2 + 2 * f2]) =
            make_float2(ox, oy);
}

extern "C" void kernel_launch(void* const* d_in, const int* in_sizes, int n_in,
                              void* d_out, int out_size, void* d_ws, size_t ws_size,
                              hipStream_t stream)
{
    const float* features    = (const float*)d_in[0];   // [N, 128]
    const float* edge_weight = (const float*)d_in[1];   // [E]
    const float* W1          = (const float*)d_in[2];   // [128, 64]
    const float* W2          = (const float*)d_in[3];   // [64, 32]
    const int*   src         = (const int*)d_in[4];     // [E]
    const int*   dst         = (const int*)d_in[5];     // [E]
    float* out = (float*)d_out;                          // [N, 32]

    // workspace layout (~52 MB)
    char* p = (char*)d_ws;
    __half* xw1h   = (__half*)p;    p += (size_t)N_NODES * H1 * 2;        // 12.8MB
    __half* h1w2h  = (__half*)p;    p += (size_t)N_NODES * H2 * 2;        // 6.4MB
    int2*  staging = (int2*)p;      p += (size_t)NBUCK * CAP * 8;         // 16.06MB
    int2*  csr     = (int2*)p;      p += (size_t)NBUCK * CAP * 8;         // 16.06MB
    int2*  seg     = (int2*)p;      p += (size_t)NBUCK * BNODES * 8;      // 0.80MB
    int*   cursor  = (int*)p;       p += 256 * 4;

    init_cursors<<<1, 256, 0, stream>>>(cursor);
    pass1_bin_gemm1<<<P1_WGS + GEMM_WGS, 256, 0, stream>>>(
        src, dst, edge_weight, cursor, staging, features, W1, xw1h);
    sort_bucket<<<NBUCK, 1024, 0, stream>>>(cursor, staging, csr, seg);

    spmm1_fused<<<SP1_BLOCKS, 256, 0, stream>>>(seg, csr, xw1h, W2, h1w2h);
    spmm_csr32h<<<(N_NODES * 64) / 256, 256, 0, stream>>>(seg, csr, h1w2h, out);
}

// Round 13
// 157.983 us; speedup vs baseline: 1.2375x; 1.2375x over previous
//
#include <hip/hip_runtime.h>
#include <hip/hip_fp16.h>

// GCN encoder: out = A @ ( relu(A @ (X W1)) W2 ),  A = COO scatter (dst <- src)
// N=100000 nodes, E=1600000 edges, F_IN=128, H1=64, H2=32, all f32.
//
// Round 13: revert r12's persistent waves (occupancy loss). spmm kernels back
// to one-wave-per-node; csr stream loads made wave-uniform int4 (scalarizable
// s_load) via readfirstlane'd segment bounds; sort_bucket pads each node's
// segment to a multiple of 4 with zero-weight edges so loops are tail-free.

constexpr int N_NODES = 100000;
constexpr int N_EDGES = 1600000;
constexpr int F_IN = 128;
constexpr int H1 = 64;
constexpr int H2 = 32;
constexpr int BSHIFT = 9;                         // 512 nodes per bucket
constexpr int BNODES = 1 << BSHIFT;
constexpr int NBUCK = (N_NODES + BNODES - 1) / BNODES;  // 196
constexpr int CAP = 10240;                        // per-bucket capacity
constexpr int CHUNK = 4096;                       // edges per binning workgroup
constexpr int P1_WGS = (N_EDGES + CHUNK - 1) / CHUNK;  // 391
constexpr int GEMM_WGS = (N_NODES + 255) / 256;        // 391

// ---------------- cursor init: cursor[b] = b*CAP ---------------------------
__global__ __launch_bounds__(256) void init_cursors(int* __restrict__ cursor)
{
    int t = threadIdx.x;
    if (t < NBUCK) cursor[t] = t * CAP;
}

// ---- pass1: gemm1 blocks first, then binning blocks -----------------------
// staging record: .x = src | (dst_low9 << 17)   (src < 2^17), .y = w bits
__global__ __launch_bounds__(256) void pass1_bin_gemm1(
    const int* __restrict__ src, const int* __restrict__ dst,
    const float* __restrict__ w, int* __restrict__ cursor,
    int2* __restrict__ staging,
    const float* __restrict__ X, const float* __restrict__ W1,
    __half* __restrict__ xw1out)
{
    __shared__ float smem[F_IN * H1];                // 32 KiB (both roles)

    if (blockIdx.x < GEMM_WGS) {
        // ---------------- gemm_xw1 role ----------------
        for (int i = threadIdx.x; i < F_IN * H1; i += 256) smem[i] = W1[i];
        __syncthreads();
        int row = blockIdx.x * 256 + threadIdx.x;
        if (row >= N_NODES) return;
        const float4* xr = reinterpret_cast<const float4*>(X + (size_t)row * F_IN);
        float4 acc[H1 / 4];
#pragma unroll
        for (int j = 0; j < H1 / 4; ++j) acc[j] = make_float4(0.f, 0.f, 0.f, 0.f);
        for (int k4 = 0; k4 < F_IN / 4; ++k4) {
            float4 xv = xr[k4];
#pragma unroll
            for (int kk = 0; kk < 4; ++kk) {
                float xk = (kk == 0) ? xv.x : (kk == 1) ? xv.y
                         : (kk == 2) ? xv.z : xv.w;
                const float4* wr = reinterpret_cast<const float4*>(
                    &smem[(k4 * 4 + kk) * H1]);
#pragma unroll
                for (int j = 0; j < H1 / 4; ++j) {
                    float4 wv = wr[j];
                    acc[j].x += xk * wv.x;
                    acc[j].y += xk * wv.y;
                    acc[j].z += xk * wv.z;
                    acc[j].w += xk * wv.w;
                }
            }
        }
        __half2* oh = reinterpret_cast<__half2*>(xw1out + (size_t)row * H1);
#pragma unroll
        for (int j = 0; j < H1 / 4; ++j) {
            oh[j * 2 + 0] = __floats2half2_rn(acc[j].x, acc[j].y);
            oh[j * 2 + 1] = __floats2half2_rn(acc[j].z, acc[j].w);
        }
        return;
    }

    // ---------------- binning role (16 edges per thread) ----------------
    int* lcnt  = (int*)smem;        // [256] counters, then reused as cursors
    int* lbase = lcnt + 256;        // [256] reserved global bases

    int e0 = (blockIdx.x - GEMM_WGS) * CHUNK;
    int nhere = N_EDGES - e0; if (nhere > CHUNK) nhere = CHUNK;  // 4096 or 2560

    lcnt[threadIdx.x] = 0;
    __syncthreads();

    int   es[16];
    int   ed[16];
    float ew[16];
    {
        bool v = (threadIdx.x * 16) < nhere;         // nhere % 16 == 0
        int tb = e0 + threadIdx.x * 16;
        if (v) {
            const int4* sp = reinterpret_cast<const int4*>(src + tb);
            const int4* dp = reinterpret_cast<const int4*>(dst + tb);
            const float4* wp = reinterpret_cast<const float4*>(w + tb);
#pragma unroll
            for (int q = 0; q < 4; ++q) {
                int4 sv = sp[q], dv = dp[q]; float4 wv = wp[q];
                es[4*q+0]=sv.x; es[4*q+1]=sv.y; es[4*q+2]=sv.z; es[4*q+3]=sv.w;
                ed[4*q+0]=dv.x; ed[4*q+1]=dv.y; ed[4*q+2]=dv.z; ed[4*q+3]=dv.w;
                ew[4*q+0]=wv.x; ew[4*q+1]=wv.y; ew[4*q+2]=wv.z; ew[4*q+3]=wv.w;
            }
        } else {
#pragma unroll
            for (int k = 0; k < 16; ++k) { es[k]=0; ed[k]=-1; ew[k]=0.f; }
        }
    }
#pragma unroll
    for (int k = 0; k < 16; ++k)
        if (ed[k] >= 0) atomicAdd(&lcnt[ed[k] >> BSHIFT], 1);
    __syncthreads();
    if (threadIdx.x < NBUCK) {
        int c = lcnt[threadIdx.x];
        lbase[threadIdx.x] = (c > 0) ? atomicAdd(&cursor[threadIdx.x], c) : 0;
    }
    __syncthreads();
    lcnt[threadIdx.x] = 0;                            // reuse as cursors
    __syncthreads();
#pragma unroll
    for (int k = 0; k < 16; ++k) {
        if (ed[k] >= 0) {
            int b = ed[k] >> BSHIFT;
            int r = atomicAdd(&lcnt[b], 1);
            int pos = lbase[b] + r;
            if (pos < (b + 1) * CAP)                  // capacity guard
                staging[pos] = make_int2(
                    es[k] | ((ed[k] & (BNODES - 1)) << 17),
                    __float_as_int(ew[k]));
        }
    }
}

// ---- sort_bucket: LDS counting sort -> csr + seg (4-aligned, 0-padded) ----
// seg[node] = {start, padded_count}; padded entries are {src=0, w=0}.
__global__ __launch_bounds__(1024) void sort_bucket(
    const int* __restrict__ cursor, const int2* __restrict__ staging,
    int2* __restrict__ csr, int2* __restrict__ seg)
{
    __shared__ int  lcnt[BNODES];                    // 2 KiB
    __shared__ int  lofs[BNODES];                    // 2 KiB
    __shared__ int2 sorted[CAP];                     // 80 KiB
    __shared__ int  total_sh;

    int b = blockIdx.x, t = threadIdx.x;
    int base = b * CAP;
    int cnt = cursor[b] - base; if (cnt > CAP) cnt = CAP;

    if (t < BNODES) lcnt[t] = 0;
    __syncthreads();

    for (int j = t; j < cnt; j += 1024)
        atomicAdd(&lcnt[(staging[base + j].x >> 17) & (BNODES - 1)], 1);
    __syncthreads();

    int v = (t < BNODES) ? lcnt[t] : 0;              // true count
    int pc = (v + 3) & ~3;                           // padded to multiple of 4
    if (t < BNODES) lofs[t] = pc;
    __syncthreads();
    for (int off = 1; off < BNODES; off <<= 1) {
        int add = (t >= off && t < BNODES) ? lofs[t - off] : 0;
        __syncthreads();
        if (t < BNODES) lofs[t] += add;
        __syncthreads();
    }
    if (t < BNODES) {
        int pexcl = lofs[t] - pc;                    // padded exclusive prefix
        seg[b * BNODES + t] = make_int2(base + pexcl, pc);
        lcnt[t] = pexcl;                             // running scatter cursors
        // zero-weight padding in [pexcl+v, pexcl+pc)
        for (int j = v; j < pc; ++j)
            if (pexcl + j < CAP) sorted[pexcl + j] = make_int2(0, 0);
        if (t == BNODES - 1) {
            int tot = lofs[t]; if (tot > CAP) tot = CAP;
            total_sh = tot;
        }
    }
    __syncthreads();

    for (int j = t; j < cnt; j += 1024) {
        int2 c = staging[base + j];
        int node = (c.x >> 17) & (BNODES - 1);
        int pos = atomicAdd(&lcnt[node], 1);
        if (pos < CAP) sorted[pos] = make_int2(c.x & 0x1FFFF, c.y);
    }
    __syncthreads();

    int total = total_sh;
    for (int j = t; j < total; j += 1024) csr[base + j] = sorted[j];
}

// ---- layer1 SpMM + fused relu + W2: one wave per node ---------------------
// csr read as uniform int4 (2 entries) -> scalar loads; parity selects entry.
// Lane gathers half2 (2 feats); 2 gathers in flight per lane.
__global__ __launch_bounds__(256) void spmm1_fused(
    const int2* __restrict__ seg, const int2* __restrict__ csr,
    const __half* __restrict__ xin, const float* __restrict__ W2,
    __half* __restrict__ h1w2h)
{
    int gid = blockIdx.x * 256 + threadIdx.x;        // grid covers N*64 exactly
    int node = __builtin_amdgcn_readfirstlane(gid >> 6);
    int f = gid & 63;
    int par = f >> 5;                                // edge parity
    int f2 = f & 31;                                 // feature pair: 2f2, 2f2+1

    // preload W2[par*32 .. +31][f2] into registers (cache-resident)
    float w2r[32];
#pragma unroll
    for (int kk = 0; kk < 32; ++kk)
        w2r[kk] = W2[(par * 32 + kk) * H2 + f2];

    int2 s = seg[node];
    int start = __builtin_amdgcn_readfirstlane(s.x);
    int cntp  = __builtin_amdgcn_readfirstlane(s.y); // multiple of 4
    const int4* csr4 = reinterpret_cast<const int4*>(csr);

    float2 a0 = make_float2(0.f, 0.f), a1 = make_float2(0.f, 0.f);
    for (int e = start; e < start + cntp; e += 4) {  // 2 edges per parity
        int4 p0 = csr4[(e >> 1) + 0];                // entries e, e+1 (uniform)
        int4 p1 = csr4[(e >> 1) + 1];                // entries e+2, e+3
        int  sA = par ? p0.z : p0.x;
        float wA = __int_as_float(par ? p0.w : p0.y);
        int  sB = par ? p1.z : p1.x;
        float wB = __int_as_float(par ? p1.w : p1.y);
        float2 xA = __half22float2(
            *reinterpret_cast<const __half2*>(&xin[(size_t)sA * H1 + 2 * f2]));
        float2 xB = __half22float2(
            *reinterpret_cast<const __half2*>(&xin[(size_t)sB * H1 + 2 * f2]));
        a0.x += wA * xA.x; a0.y += wA * xA.y;
        a1.x += wB * xB.x; a1.y += wB * xB.y;
    }
    float rx = a0.x + a1.x, ry = a0.y + a1.y;
    rx += __shfl_xor(rx, 32, 64);                    // combine parities
    ry += __shfl_xor(ry, 32, 64);
    rx = fmaxf(rx, 0.f); ry = fmaxf(ry, 0.f);        // relu(h1) pair

    // o[j=f2] partial over k = par*32 + kk; pair p = 16*par + kk/2
    float o = 0.f;
#pragma unroll
    for (int kk = 0; kk < 32; kk += 2) {
        int p = 16 * par + (kk >> 1);
        o += __shfl(rx, p, 64) * w2r[kk];
        o += __shfl(ry, p, 64) * w2r[kk + 1];
    }
    o += __shfl_xor(o, 32, 64);
    if (f < 32)
        h1w2h[(size_t)node * H2 + f2] = __float2half(o);
}

// ---- layer 2 SpMM: wave per node, quarter-waves on edge slots -------------
// csr read as uniform int4 pairs; slot selects its entry. Tail-free (pad 4).
__global__ __launch_bounds__(256) void spmm_csr32h(
    const int2* __restrict__ seg, const int2* __restrict__ csr,
    const __half* __restrict__ xin, float* __restrict__ out)
{
    int gid = blockIdx.x * 256 + threadIdx.x;        // grid covers N*64 exactly
    int node = __builtin_amdgcn_readfirstlane(gid >> 6);
    int lane = gid & 63;
    int slot = lane >> 4;                            // edge slot 0..3
    int f2 = lane & 15;                              // feature pair: 2f2, 2f2+1

    int2 s = seg[node];
    int start = __builtin_amdgcn_readfirstlane(s.x);
    int cntp  = __builtin_amdgcn_readfirstlane(s.y); // multiple of 4
    int endp = start + cntp;
    const int4* csr4 = reinterpret_cast<const int4*>(csr);

    float2 a0 = make_float2(0.f, 0.f), a1 = make_float2(0.f, 0.f);
    int e = start;
    for (; e + 8 <= endp; e += 8) {                  // 2 edges per slot
        int4 q0 = csr4[(e >> 1) + 0];                // entries e, e+1
        int4 q1 = csr4[(e >> 1) + 1];                // entries e+2, e+3
        int4 q2 = csr4[(e >> 1) + 2];                // entries e+4, e+5
        int4 q3 = csr4[(e >> 1) + 3];                // entries e+6, e+7
        int4 qa = (slot & 2) ? q1 : q0;
        int  sA = (slot & 1) ? qa.z : qa.x;
        float wA = __int_as_float((slot & 1) ? qa.w : qa.y);
        int4 qb = (slot & 2) ? q3 : q2;
        int  sB = (slot & 1) ? qb.z : qb.x;
        float wB = __int_as_float((slot & 1) ? qb.w : qb.y);
        float2 xA = __half22float2(
            *reinterpret_cast<const __half2*>(&xin[(size_t)sA * H2 + 2 * f2]));
        float2 xB = __half22float2(
            *reinterpret_cast<const __half2*>(&xin[(size_t)sB * H2 + 2 * f2]));
        a0.x += wA * xA.x; a0.y += wA * xA.y;
        a1.x += wB * xB.x; a1.y += wB * xB.y;
    }
    if (e < endp) {                                  // one 4-group tail
        int4 q0 = csr4[(e >> 1) + 0];
        int4 q1 = csr4[(e >> 1) + 1];
        int4 qa = (slot & 2) ? q1 : q0;
        int  sA = (slot & 1) ? qa.z : qa.x;
        float wA = __int_as_float((slot & 1) ? qa.w : qa.y);
        float2 xA = __half22float2(
            *reinterpret_cast<const __half2*>(&xin[(size_t)sA * H2 + 2 * f2]));
        a0.x += wA * xA.x; a0.y += wA * xA.y;
    }
    float ox = a0.x + a1.x, oy = a0.y + a1.y;
    ox += __shfl_xor(ox, 16, 64); oy += __shfl_xor(oy, 16, 64);
    ox += __shfl_xor(ox, 32, 64); oy += __shfl_xor(oy, 32, 64);
    if (lane < 16)
        *reinterpret_cast<float2*>(&out[(size_t)node * H2 + 2 * f2]) =
            make_float2(ox, oy);
}

extern "C" void kernel_launch(void* const* d_in, const int* in_sizes, int n_in,
                              void* d_out, int out_size, void* d_ws, size_t ws_size,
                              hipStream_t stream)
{
    const float* features    = (const float*)d_in[0];   // [N, 128]
    const float* edge_weight = (const float*)d_in[1];   // [E]
    const float* W1          = (const float*)d_in[2];   // [128, 64]
    const float* W2          = (const float*)d_in[3];   // [64, 32]
    const int*   src         = (const int*)d_in[4];     // [E]
    const int*   dst         = (const int*)d_in[5];     // [E]
    float* out = (float*)d_out;                          // [N, 32]

    // workspace layout (~52 MB)
    char* p = (char*)d_ws;
    __half* xw1h   = (__half*)p;    p += (size_t)N_NODES * H1 * 2;        // 12.8MB
    __half* h1w2h  = (__half*)p;    p += (size_t)N_NODES * H2 * 2;        // 6.4MB
    int2*  staging = (int2*)p;      p += (size_t)NBUCK * CAP * 8;         // 16.06MB
    int2*  csr     = (int2*)p;      p += (size_t)NBUCK * CAP * 8;         // 16.06MB
    int2*  seg     = (int2*)p;      p += (size_t)NBUCK * BNODES * 8;      // 0.80MB
    int*   cursor  = (int*)p;       p += 256 * 4;

    init_cursors<<<1, 256, 0, stream>>>(cursor);
    pass1_bin_gemm1<<<P1_WGS + GEMM_WGS, 256, 0, stream>>>(
        src, dst, edge_weight, cursor, staging, features, W1, xw1h);
    sort_bucket<<<NBUCK, 1024, 0, stream>>>(cursor, staging, csr, seg);

    spmm1_fused<<<(N_NODES * 64) / 256, 256, 0, stream>>>(seg, csr, xw1h, W2, h1w2h);
    spmm_csr32h<<<(N_NODES * 64) / 256, 256, 0, stream>>>(seg, csr, h1w2h, out);
}